// Round 1
// baseline (816.246 us; speedup 1.0000x reference)
//
#include <hip/hip_runtime.h>
#include <hip/hip_bf16.h>
#include <stdint.h>

// ---------- types ----------
typedef __bf16 bf16x8 __attribute__((ext_vector_type(8)));
typedef float  f32x4  __attribute__((ext_vector_type(4)));
typedef unsigned short u16x8 __attribute__((ext_vector_type(8)));

#define HS   1024      // hidden size
#define FOURH 4096
#define SEQ  512
#define BATCH 64

// manual round-to-nearest-even f32 -> bf16 bits (inputs are tame, no NaN handling)
__device__ __forceinline__ unsigned short f2bf(float f) {
    unsigned u = __builtin_bit_cast(unsigned, f);
    u = (u + 0x7FFFu + ((u >> 16) & 1u)) >> 16;
    return (unsigned short)u;
}

__device__ __forceinline__ void gload_lds16(const void* g, void* l) {
    __builtin_amdgcn_global_load_lds(
        (const __attribute__((address_space(1))) void*)g,
        (__attribute__((address_space(3))) void*)l, 16, 0, 0);
}

// ---------- kernel 1: x (f32) -> Xb (bf16), vectorized 8/thread/iter ----------
__global__ __launch_bounds__(256) void convert_x(const float* __restrict__ x,
                                                 unsigned short* __restrict__ xb,
                                                 long n8) {
    long i = (long)blockIdx.x * blockDim.x + threadIdx.x;
    long stride = (long)gridDim.x * blockDim.x;
    for (; i < n8; i += stride) {
        const float4* p = (const float4*)(x + i * 8);
        float4 a = p[0], b = p[1];
        u16x8 o;
        o[0] = f2bf(a.x); o[1] = f2bf(a.y); o[2] = f2bf(a.z); o[3] = f2bf(a.w);
        o[4] = f2bf(b.x); o[5] = f2bf(b.y); o[6] = f2bf(b.z); o[7] = f2bf(b.w);
        *(u16x8*)(xb + i * 8) = o;
    }
}

// ---------- kernel 2: U [1024][4096] f32 -> Ut [4096][1024] bf16 ----------
__global__ __launch_bounds__(256) void transpose_u(const float* __restrict__ U,
                                                   unsigned short* __restrict__ Ut) {
    __shared__ float tile[32][33];
    int bx = blockIdx.x;            // 4096 blocks
    int tn = bx >> 5;               // 0..127  (n tile)
    int tk = bx & 31;               // 0..31   (k tile)
    int c = threadIdx.x & 31;       // 0..31
    int r = threadIdx.x >> 5;       // 0..7
#pragma unroll
    for (int i = 0; i < 4; ++i) {
        int k = tk * 32 + r + i * 8;
        tile[r + i * 8][c] = U[(size_t)k * FOURH + tn * 32 + c];
    }
    __syncthreads();
#pragma unroll
    for (int i = 0; i < 4; ++i) {
        int nl = r + i * 8;
        Ut[(size_t)(tn * 32 + nl) * HS + tk * 32 + c] = f2bf(tile[c][nl]);
    }
}

// ---------- kernel 3: bf16 GEMM gates = act(Xrows @ Ut^T + bias), f32 out ----------
// m97-structure: BM=BN=128, BK=32, 256 threads = 4 waves (2x2), 16x16x32 MFMA.
__global__ __launch_bounds__(256) void gemm_gates(
    const unsigned short* __restrict__ Xb,   // [B*S][1024] bf16
    const unsigned short* __restrict__ Ut,   // [4096][1024] bf16
    const float* __restrict__ bias,          // [4096]
    float* __restrict__ gates,               // [64*chunk][4096] activated f32
    int lg2chunk, int s0) {
    __shared__ unsigned short As[128 * 32];  // 8KB, row-major [row][k]
    __shared__ unsigned short Bs[128 * 32];  // 8KB, row-major [n][k]

    int bx = blockIdx.x;
    int mt = bx >> 5;        // 32 n-tiles
    int nt = bx & 31;
    int tid = threadIdx.x;
    int w = tid >> 6, l = tid & 63;
    int wr = w >> 1, wc = w & 1;
    int lr = l & 15, lg = l >> 4;

    f32x4 acc[4][4];
#pragma unroll
    for (int mi = 0; mi < 4; ++mi)
#pragma unroll
        for (int ni = 0; ni < 4; ++ni) acc[mi][ni] = 0.f;

    const int aoff = (wr * 64 + lr) * 32 + lg * 8;
    const int boff = (wc * 64 + lr) * 32 + lg * 8;
    const int rA0 = mt * 128, rB0 = nt * 128;
    const int cmask = (1 << lg2chunk) - 1;

    // per-lane staging geometry: chunk c covers 16 rows; lane l -> row c*16+l/4, col (l&3)*8
    const int srow = l >> 2;
    const int scol = (l & 3) * 8;

    for (int k0 = 0; k0 < 1024; k0 += 32) {
        if (k0) __syncthreads();
#pragma unroll
        for (int i = 0; i < 2; ++i) {
            int c = w * 2 + i;
            int row = c * 16 + srow;
            int mrow = rA0 + row;
            int b = mrow >> lg2chunk;
            int sl = mrow & cmask;
            const unsigned short* gA = Xb + (size_t)(b * SEQ + s0 + sl) * HS + k0 + scol;
            gload_lds16(gA, &As[c * 512]);
            int nrow = rB0 + row;
            const unsigned short* gB = Ut + (size_t)nrow * HS + k0 + scol;
            gload_lds16(gB, &Bs[c * 512]);
        }
        __syncthreads();
        bf16x8 afr[4], bfr[4];
#pragma unroll
        for (int mi = 0; mi < 4; ++mi)
            afr[mi] = *(const bf16x8*)&As[aoff + mi * 16 * 32];
#pragma unroll
        for (int ni = 0; ni < 4; ++ni)
            bfr[ni] = *(const bf16x8*)&Bs[boff + ni * 16 * 32];
#pragma unroll
        for (int mi = 0; mi < 4; ++mi)
#pragma unroll
            for (int ni = 0; ni < 4; ++ni)
                acc[mi][ni] = __builtin_amdgcn_mfma_f32_16x16x32_bf16(
                    afr[mi], bfr[ni], acc[mi][ni], 0, 0, 0);
    }

    // epilogue: bias + activation, f32 store. C/D map: col=lane&15, row=(lane>>4)*4+r
#pragma unroll
    for (int ni = 0; ni < 4; ++ni) {
        int gcol = nt * 128 + wc * 64 + ni * 16 + lr;
        bool is_g = ((gcol >> 10) == 2);
        float bv = bias[gcol];
#pragma unroll
        for (int mi = 0; mi < 4; ++mi) {
#pragma unroll
            for (int r = 0; r < 4; ++r) {
                int grow = mt * 128 + wr * 64 + mi * 16 + lg * 4 + r;
                float v = acc[mi][ni][r] + bv;
                float e;
                if (is_g) e = 1.f - 2.f / (1.f + __expf(2.f * v));   // tanh
                else      e = 1.f / (1.f + __expf(-v));              // sigmoid
                gates[(size_t)grow * FOURH + gcol] = e;
            }
        }
    }
}

// ---------- kernel 4: recurrence, one thread per (b,h) chain ----------
__global__ __launch_bounds__(256) void lstm_recur(
    const float* __restrict__ gates,  // [64*chunk][4096] activated
    float* __restrict__ out,          // d_out base (f32)
    float* __restrict__ cstate,       // [65536]
    int chunk, int s0) {
    int t = blockIdx.x * 256 + threadIdx.x;  // 0..65535
    int b = t >> 10, h = t & 1023;
    float c = (s0 == 0) ? 0.f : cstate[t];
    const float* gp = gates + (size_t)b * chunk * FOURH + h;
    float* op = out + (size_t)(b * SEQ + s0) * HS + h;
    float hv = 0.f;
#pragma unroll 8
    for (int sl = 0; sl < chunk; ++sl) {
        float iv = gp[0];
        float fv = gp[1024];
        float gv = gp[2048];
        float ov = gp[3072];
        c = fv * c + iv * gv;
        float th = 1.f - 2.f / (1.f + __expf(2.f * c));
        hv = ov * th;
        *op = hv;
        gp += FOURH;
        op += HS;
    }
    cstate[t] = c;
    if (s0 + chunk == SEQ) {
        out[(size_t)BATCH * SEQ * HS + t] = hv;                      // h_T
        out[(size_t)BATCH * SEQ * HS + BATCH * HS + t] = c;          // c_T
    }
}

// ---------- launcher ----------
extern "C" void kernel_launch(void* const* d_in, const int* in_sizes, int n_in,
                              void* d_out, int out_size, void* d_ws, size_t ws_size,
                              hipStream_t stream) {
    const float* x    = (const float*)d_in[0];
    const float* U    = (const float*)d_in[1];
    const float* bias = (const float*)d_in[2];
    float* out = (float*)d_out;
    char*  ws  = (char*)d_ws;

    // ws layout
    unsigned short* Xb = (unsigned short*)ws;                   // 64MB  bf16 x
    unsigned short* Ut = (unsigned short*)(ws + 67108864);      // 8MB   bf16 U^T
    float* cstate      = (float*)(ws + 75497472);               // 256KB
    float* gates       = (float*)(ws + 75759616);               // chunk*1MB
    const size_t fixed = 75759616;

    int chunk = 512;
    while (chunk > 2 && fixed + (size_t)BATCH * chunk * FOURH * 4 > ws_size)
        chunk >>= 1;
    int lg2 = 31 - __builtin_clz(chunk);

    convert_x<<<2048, 256, 0, stream>>>(x, Xb, (long)BATCH * SEQ * HS / 8);
    transpose_u<<<4096, 256, 0, stream>>>(U, Ut);

    for (int s0 = 0; s0 < SEQ; s0 += chunk) {
        int mtiles = (BATCH * chunk) / 128;
        gemm_gates<<<mtiles * 32, 256, 0, stream>>>(Xb, Ut, bias, gates, lg2, s0);
        lstm_recur<<<256, 256, 0, stream>>>(gates, out, cstate, chunk, s0);
    }
}

// Round 2
// 807.099 us; speedup vs baseline: 1.0113x; 1.0113x over previous
//
#include <hip/hip_runtime.h>
#include <hip/hip_bf16.h>
#include <stdint.h>

// ---------- types ----------
typedef __bf16 bf16x8 __attribute__((ext_vector_type(8)));
typedef float  f32x4  __attribute__((ext_vector_type(4)));
typedef unsigned short u16x8 __attribute__((ext_vector_type(8)));

#define HS    1024     // hidden size
#define FOURH 4096
#define SEQ   512
#define BATCH 64

// manual round-to-nearest-even f32 -> bf16 bits
__device__ __forceinline__ unsigned short f2bf(float f) {
    unsigned u = __builtin_bit_cast(unsigned, f);
    u = (u + 0x7FFFu + ((u >> 16) & 1u)) >> 16;
    return (unsigned short)u;
}

__device__ __forceinline__ void gload_lds16(const void* g, void* l) {
    __builtin_amdgcn_global_load_lds(
        (const __attribute__((address_space(1))) void*)g,
        (__attribute__((address_space(3))) void*)l, 16, 0, 0);
}

// ---------- kernel 1: x (f32) -> Xb (bf16) ----------
__global__ __launch_bounds__(256) void convert_x(const float* __restrict__ x,
                                                 unsigned short* __restrict__ xb,
                                                 long n8) {
    long i = (long)blockIdx.x * blockDim.x + threadIdx.x;
    long stride = (long)gridDim.x * blockDim.x;
    for (; i < n8; i += stride) {
        const float4* p = (const float4*)(x + i * 8);
        float4 a = p[0], b = p[1];
        u16x8 o;
        o[0] = f2bf(a.x); o[1] = f2bf(a.y); o[2] = f2bf(a.z); o[3] = f2bf(a.w);
        o[4] = f2bf(b.x); o[5] = f2bf(b.y); o[6] = f2bf(b.z); o[7] = f2bf(b.w);
        *(u16x8*)(xb + i * 8) = o;
    }
}

// ---------- kernel 2: U [1024][4096] f32 -> Ut [4096][1024] bf16 ----------
__global__ __launch_bounds__(256) void transpose_u(const float* __restrict__ U,
                                                   unsigned short* __restrict__ Ut) {
    __shared__ float tile[32][33];
    int bx = blockIdx.x;            // 4096 blocks
    int tn = bx >> 5;               // 0..127  (n tile)
    int tk = bx & 31;               // 0..31   (k tile)
    int c = threadIdx.x & 31;
    int r = threadIdx.x >> 5;
#pragma unroll
    for (int i = 0; i < 4; ++i) {
        int k = tk * 32 + r + i * 8;
        tile[r + i * 8][c] = U[(size_t)k * FOURH + tn * 32 + c];
    }
    __syncthreads();
#pragma unroll
    for (int i = 0; i < 4; ++i) {
        int nl = r + i * 8;
        Ut[(size_t)(tn * 32 + nl) * HS + tk * 32 + c] = f2bf(tile[c][nl]);
    }
}

// ---------- kernel 3: 256x256 8-wave pipelined bf16 GEMM, fused act epilogue ----
// gates = act(X @ Ut^T + bias).  BM=BN=256, BK=64, 512 thr (8 waves 2x4),
// double-buffered LDS 128KB, st_16x32 XOR swizzle, counted vmcnt(4), setprio.
__global__ __launch_bounds__(512) void gemm_gates8(
    const unsigned short* __restrict__ Xb,   // [B*S][1024] bf16
    const unsigned short* __restrict__ Ut,   // [4096][1024] bf16
    const float* __restrict__ bias,          // [4096]
    float* __restrict__ gates,               // [BATCH*chunk][4096] activated f32
    int lg2chunk, int s0) {
    __shared__ unsigned short Asb[2][16384]; // 2 x 32KB : [buf][256 rows x 64 k]
    __shared__ unsigned short Bsb[2][16384]; // subtiled 16x32, k XOR-swizzled

    // T1: XCD-aware block swizzle (grid is always a multiple of 8)
    int nwg = gridDim.x;
    int bid = blockIdx.x;
    int wg = (bid & 7) * (nwg >> 3) + (bid >> 3);
    int mt = wg >> 4;            // N tiles = 4096/256 = 16
    int nt = wg & 15;

    int tid = threadIdx.x;
    int w = tid >> 6, l = tid & 63;
    int wr = w >> 2, wc = w & 3;       // wave grid 2 (M) x 4 (N)
    int lr = l & 15, lg = l >> 4;

    const int m0 = mt * 256, n0 = nt * 256;
    const int cmask = (1 << lg2chunk) - 1;

    // ds_read offset within a tile (ushort units): subtile(rs,cs)*512 + r*32 + k'
    // k' = (lg*8) ^ ((row&8)<<1)  [st_16x32 swizzle]
    const int rdo = lr * 32 + ((lg * 8) ^ (((l >> 3) & 1) << 4));

    // staging lane geometry: lane l covers subtile row l>>2, swizzled-k block (l&3)*8
    const int srow = l >> 2;
    const int skin = ((l & 3) * 8) ^ (((l >> 5) & 1) << 4);  // global k for this slot

    // per-j global source base pointers (row fixed forever; k advances per tile)
    const unsigned short* pA[2];
    const unsigned short* pB[2];
#pragma unroll
    for (int j = 0; j < 2; ++j) {
        int rs = w * 2 + j;
        int row = rs * 16 + srow;
        int mrow = m0 + row;
        int b = mrow >> lg2chunk, sl = mrow & cmask;
        pA[j] = Xb + (size_t)(b * SEQ + s0 + sl) * HS + skin;
        pB[j] = Ut + (size_t)(n0 + row) * HS + skin;
    }

    f32x4 acc[8][4];
#pragma unroll
    for (int mi = 0; mi < 8; ++mi)
#pragma unroll
        for (int ni = 0; ni < 4; ++ni) acc[mi][ni] = 0.f;

    // stage one item (X or B, one k-slice) of K-tile tk into buf tk&1
    auto STAGE = [&](int tk, int ks, bool isB) {
        unsigned short* dst = isB ? Bsb[tk & 1] : Asb[tk & 1];
        const unsigned short* const* ps = isB ? pB : pA;
        int ko = ((tk & 15) << 6) + (ks << 5);
#pragma unroll
        for (int j = 0; j < 2; ++j)
            gload_lds16(ps[j] + ko, dst + (((w * 2 + j) << 1) + ks) * 512);
    };

    // prologue: stage K-tile 0 (4 items, 8 loads in flight)
    STAGE(0, 0, false); STAGE(0, 0, true);
    STAGE(0, 1, false); STAGE(0, 1, true);

    for (int t = 0; t < 16; ++t) {
        const int buf = t & 1;
        const int nx = t + 1;
        const unsigned short* At = Asb[buf];
        const unsigned short* Bt = Bsb[buf];
        bf16x8 af[4], bfr[4];

        // sync S0: oldest 4 loads = (t,A,k0),(t,B,k0) — exactly what we need
        asm volatile("s_waitcnt vmcnt(4)" ::: "memory");
        __builtin_amdgcn_s_barrier();
        __builtin_amdgcn_sched_barrier(0);

        // ---- phase 0: k-slice 0, fragment rows 0-3 ----
        STAGE(nx, 0, false);
#pragma unroll
        for (int ni = 0; ni < 4; ++ni)
            bfr[ni] = *(const bf16x8*)(Bt + (((wc * 4 + ni) << 1) + 0) * 512 + rdo);
#pragma unroll
        for (int mi = 0; mi < 4; ++mi)
            af[mi] = *(const bf16x8*)(At + (((wr * 8 + mi) << 1) + 0) * 512 + rdo);
        __builtin_amdgcn_s_setprio(1);
#pragma unroll
        for (int mi = 0; mi < 4; ++mi)
#pragma unroll
            for (int ni = 0; ni < 4; ++ni)
                acc[mi][ni] = __builtin_amdgcn_mfma_f32_16x16x32_bf16(
                    af[mi], bfr[ni], acc[mi][ni], 0, 0, 0);
        __builtin_amdgcn_s_setprio(0);

        // ---- phase 1: k-slice 0, fragment rows 4-7 ----
        STAGE(nx, 0, true);
#pragma unroll
        for (int mi = 0; mi < 4; ++mi)
            af[mi] = *(const bf16x8*)(At + (((wr * 8 + 4 + mi) << 1) + 0) * 512 + rdo);
        __builtin_amdgcn_s_setprio(1);
#pragma unroll
        for (int mi = 0; mi < 4; ++mi)
#pragma unroll
            for (int ni = 0; ni < 4; ++ni)
                acc[4 + mi][ni] = __builtin_amdgcn_mfma_f32_16x16x32_bf16(
                    af[mi], bfr[ni], acc[4 + mi][ni], 0, 0, 0);
        __builtin_amdgcn_s_setprio(0);

        // sync S1: oldest 4 = (t,A,k1),(t,B,k1)
        asm volatile("s_waitcnt vmcnt(4)" ::: "memory");
        __builtin_amdgcn_s_barrier();
        __builtin_amdgcn_sched_barrier(0);

        // ---- phase 2: k-slice 1, fragment rows 0-3 ----
        STAGE(nx, 1, false);
#pragma unroll
        for (int ni = 0; ni < 4; ++ni)
            bfr[ni] = *(const bf16x8*)(Bt + (((wc * 4 + ni) << 1) + 1) * 512 + rdo);
#pragma unroll
        for (int mi = 0; mi < 4; ++mi)
            af[mi] = *(const bf16x8*)(At + (((wr * 8 + mi) << 1) + 1) * 512 + rdo);
        __builtin_amdgcn_s_setprio(1);
#pragma unroll
        for (int mi = 0; mi < 4; ++mi)
#pragma unroll
            for (int ni = 0; ni < 4; ++ni)
                acc[mi][ni] = __builtin_amdgcn_mfma_f32_16x16x32_bf16(
                    af[mi], bfr[ni], acc[mi][ni], 0, 0, 0);
        __builtin_amdgcn_s_setprio(0);

        // ---- phase 3: k-slice 1, fragment rows 4-7 ----
        STAGE(nx, 1, true);
#pragma unroll
        for (int mi = 0; mi < 4; ++mi)
            af[mi] = *(const bf16x8*)(At + (((wr * 8 + 4 + mi) << 1) + 1) * 512 + rdo);
        __builtin_amdgcn_s_setprio(1);
#pragma unroll
        for (int mi = 0; mi < 4; ++mi)
#pragma unroll
            for (int ni = 0; ni < 4; ++ni)
                acc[4 + mi][ni] = __builtin_amdgcn_mfma_f32_16x16x32_bf16(
                    af[mi], bfr[ni], acc[4 + mi][ni], 0, 0, 0);
        __builtin_amdgcn_s_setprio(0);
    }

    // ---- epilogue: bias + activation, f32 store ----
    // C/D map: col = lane&15, row = (lane>>4)*4 + r
#pragma unroll
    for (int ni = 0; ni < 4; ++ni) {
        int gcol = n0 + wc * 64 + ni * 16 + lr;
        bool is_g = ((gcol >> 10) == 2);
        float bv = bias[gcol];
#pragma unroll
        for (int mi = 0; mi < 8; ++mi) {
            int grow = m0 + wr * 128 + mi * 16 + lg * 4;
#pragma unroll
            for (int r = 0; r < 4; ++r) {
                float v = acc[mi][ni][r] + bv;
                float e;
                if (is_g) e = 1.f - 2.f / (1.f + __expf(2.f * v));   // tanh
                else      e = 1.f / (1.f + __expf(-v));              // sigmoid
                gates[(size_t)(grow + r) * FOURH + gcol] = e;
            }
        }
    }
}

// ---------- kernel 4: recurrence, one thread per (b,h) chain ----------
__global__ __launch_bounds__(256) void lstm_recur(
    const float* __restrict__ gates,  // [64*chunk][4096] activated
    float* __restrict__ out,          // d_out base (f32)
    float* __restrict__ cstate,       // [65536]
    int chunk, int s0) {
    int t = blockIdx.x * 256 + threadIdx.x;  // 0..65535
    int b = t >> 10, h = t & 1023;
    float c = (s0 == 0) ? 0.f : cstate[t];
    const float* gp = gates + (size_t)b * chunk * FOURH + h;
    float* op = out + (size_t)(b * SEQ + s0) * HS + h;
    float hv = 0.f;
#pragma unroll 8
    for (int sl = 0; sl < chunk; ++sl) {
        float iv = gp[0];
        float fv = gp[1024];
        float gv = gp[2048];
        float ov = gp[3072];
        c = fv * c + iv * gv;
        float th = 1.f - 2.f / (1.f + __expf(2.f * c));
        hv = ov * th;
        *op = hv;
        gp += FOURH;
        op += HS;
    }
    cstate[t] = c;
    if (s0 + chunk == SEQ) {
        out[(size_t)BATCH * SEQ * HS + t] = hv;                      // h_T
        out[(size_t)BATCH * SEQ * HS + BATCH * HS + t] = c;          // c_T
    }
}

// ---------- launcher ----------
extern "C" void kernel_launch(void* const* d_in, const int* in_sizes, int n_in,
                              void* d_out, int out_size, void* d_ws, size_t ws_size,
                              hipStream_t stream) {
    const float* x    = (const float*)d_in[0];
    const float* U    = (const float*)d_in[1];
    const float* bias = (const float*)d_in[2];
    float* out = (float*)d_out;
    char*  ws  = (char*)d_ws;

    // ws layout
    unsigned short* Xb = (unsigned short*)ws;                   // 64MB  bf16 x
    unsigned short* Ut = (unsigned short*)(ws + 67108864);      // 8MB   bf16 U^T
    float* cstate      = (float*)(ws + 75497472);               // 256KB
    float* gates       = (float*)(ws + 75759616);               // chunk*1MB
    const size_t fixed = 75759616;

    int chunk = 512;
    while (chunk > 4 && fixed + (size_t)BATCH * chunk * FOURH * 4 > ws_size)
        chunk >>= 1;
    int lg2 = 31 - __builtin_clz(chunk);

    convert_x<<<2048, 256, 0, stream>>>(x, Xb, (long)BATCH * SEQ * HS / 8);
    transpose_u<<<4096, 256, 0, stream>>>(U, Ut);

    for (int s0 = 0; s0 < SEQ; s0 += chunk) {
        int mtiles = (BATCH * chunk) / 256;          // chunk>=4 -> integer
        gemm_gates8<<<mtiles * 16, 512, 0, stream>>>(Xb, Ut, bias, gates, lg2, s0);
        lstm_recur<<<256, 256, 0, stream>>>(gates, out, cstate, chunk, s0);
    }
}

// Round 3
// 574.930 us; speedup vs baseline: 1.4197x; 1.4038x over previous
//
#include <hip/hip_runtime.h>
#include <hip/hip_bf16.h>
#include <stdint.h>

// ---------- types ----------
typedef __bf16 bf16x8 __attribute__((ext_vector_type(8)));
typedef float  f32x4  __attribute__((ext_vector_type(4)));
typedef unsigned short u16x8 __attribute__((ext_vector_type(8)));

#define HS    1024     // hidden size
#define FOURH 4096
#define SEQ   512
#define BATCH 64

// manual round-to-nearest-even f32 -> bf16 bits
__device__ __forceinline__ unsigned short f2bf(float f) {
    unsigned u = __builtin_bit_cast(unsigned, f);
    u = (u + 0x7FFFu + ((u >> 16) & 1u)) >> 16;
    return (unsigned short)u;
}

__device__ __forceinline__ void gload_lds16(const void* g, void* l) {
    __builtin_amdgcn_global_load_lds(
        (const __attribute__((address_space(1))) void*)g,
        (__attribute__((address_space(3))) void*)l, 16, 0, 0);
}

// ---------- kernel 1: x (f32) -> Xb (bf16) ----------
__global__ __launch_bounds__(256) void convert_x(const float* __restrict__ x,
                                                 unsigned short* __restrict__ xb,
                                                 long n8) {
    long i = (long)blockIdx.x * blockDim.x + threadIdx.x;
    long stride = (long)gridDim.x * blockDim.x;
    for (; i < n8; i += stride) {
        const float4* p = (const float4*)(x + i * 8);
        float4 a = p[0], b = p[1];
        u16x8 o;
        o[0] = f2bf(a.x); o[1] = f2bf(a.y); o[2] = f2bf(a.z); o[3] = f2bf(a.w);
        o[4] = f2bf(b.x); o[5] = f2bf(b.y); o[6] = f2bf(b.z); o[7] = f2bf(b.w);
        *(u16x8*)(xb + i * 8) = o;
    }
}

// ---------- kernel 2: U [1024][4096] f32 -> Ut [4096][1024] bf16 ----------
__global__ __launch_bounds__(256) void transpose_u(const float* __restrict__ U,
                                                   unsigned short* __restrict__ Ut) {
    __shared__ float tile[32][33];
    int bx = blockIdx.x;            // 4096 blocks
    int tn = bx >> 5;               // n tile
    int tk = bx & 31;               // k tile
    int c = threadIdx.x & 31;
    int r = threadIdx.x >> 5;
#pragma unroll
    for (int i = 0; i < 4; ++i) {
        int k = tk * 32 + r + i * 8;
        tile[r + i * 8][c] = U[(size_t)k * FOURH + tn * 32 + c];
    }
    __syncthreads();
#pragma unroll
    for (int i = 0; i < 4; ++i) {
        int nl = r + i * 8;
        Ut[(size_t)(tn * 32 + nl) * HS + tk * 32 + c] = f2bf(tile[c][nl]);
    }
}

// ---------- kernel 3: 256x256 ring-4 pipelined bf16 GEMM, fused act -> f16 ----
// BM=BN=256, BK=32, 512 thr (8 waves 2Mx4N), LDS ring of 4 tile-slots (128KB),
// st_16x32 XOR swizzle, counted vmcnt(8) (3 K-tiles in flight), setprio.
__global__ __launch_bounds__(512) void gemm_gates8(
    const unsigned short* __restrict__ Xb,   // [B*S][1024] bf16
    const unsigned short* __restrict__ Ut,   // [4096][1024] bf16
    const float* __restrict__ bias,          // [4096]
    _Float16* __restrict__ gates,            // [BATCH*chunk][4096] activated f16
    int lg2chunk, int s0) {
    __shared__ unsigned short As[4][8192];   // 4 x 16KB : [slot][256 rows x 32 k]
    __shared__ unsigned short Bs[4][8192];   // subtiled 16x32, k XOR-swizzled

    // T1: XCD-aware block swizzle (nwg always multiple of 8)
    int nwg = gridDim.x;
    int bid = blockIdx.x;
    int wg = (bid & 7) * (nwg >> 3) + (bid >> 3);
    int mt = wg >> 4;            // 16 n-tiles (4096/256)
    int nt = wg & 15;

    int tid = threadIdx.x;
    int w = tid >> 6, l = tid & 63;
    int wr = w >> 2, wc = w & 3;       // wave grid 2 (M) x 4 (N)
    int lr = l & 15, lg = l >> 4;

    const int m0 = mt * 256, n0 = nt * 256;
    const int cmask = (1 << lg2chunk) - 1;

    // ds_read offset within a 16x32 subtile (ushort units), st_16x32 swizzle
    const int rdo = lr * 32 + ((lg * 8) ^ ((lr & 8) << 1));

    // staging lane geometry: lane l -> subtile row l>>2, swizzled-k slot (l&3)*8
    const int srow = l >> 2;
    const int skin = ((l & 3) * 8) ^ (((l >> 5) & 1) << 4);  // global k for slot

    // per-j global source base pointers (row fixed; k advances per tile)
    const unsigned short* pA[2];
    const unsigned short* pB[2];
#pragma unroll
    for (int j = 0; j < 2; ++j) {
        int row = (w * 2 + j) * 16 + srow;       // 0..255
        int mrow = m0 + row;
        int b = mrow >> lg2chunk, sl = mrow & cmask;
        pA[j] = Xb + (size_t)(b * SEQ + s0 + sl) * HS + skin;
        pB[j] = Ut + (size_t)(n0 + row) * HS + skin;
    }

    f32x4 acc[8][4];
#pragma unroll
    for (int mi = 0; mi < 8; ++mi)
#pragma unroll
        for (int ni = 0; ni < 4; ++ni) acc[mi][ni] = 0.f;

    // stage one matrix half (2 gload_lds) of K-tile t into slot t&3
    auto STAGE = [&](int t, bool isB) {
        unsigned short* dst = (isB ? &Bs[t & 3][0] : &As[t & 3][0]) + (w * 2) * 512;
        const unsigned short* const* ps = isB ? pB : pA;
        int ko = t * 32;
        gload_lds16(ps[0] + ko, dst);
        gload_lds16(ps[1] + ko, dst + 512);
    };

    // prologue: stage K-tiles 0,1,2 (12 loads in flight)
    STAGE(0, false); STAGE(0, true);
    STAGE(1, false); STAGE(1, true);
    STAGE(2, false); STAGE(2, true);

    for (int t = 0; t < 32; ++t) {
        const unsigned short* At = As[t & 3];
        const unsigned short* Bt = Bs[t & 3];
        bf16x8 af[4], bfr[4];

        // tile-start sync: oldest loads beyond 8 outstanding = this tile's
        if (t < 30)       asm volatile("s_waitcnt vmcnt(8)" ::: "memory");
        else if (t == 30) asm volatile("s_waitcnt vmcnt(4)" ::: "memory");
        else              asm volatile("s_waitcnt vmcnt(0)" ::: "memory");
        __builtin_amdgcn_s_barrier();
        __builtin_amdgcn_sched_barrier(0);

        // ---- phase A: M-frag rows 0-3 (+ stage A of t+3) ----
        if (t + 3 < 32) STAGE(t + 3, false);
#pragma unroll
        for (int ni = 0; ni < 4; ++ni)
            bfr[ni] = *(const bf16x8*)(Bt + (wc * 4 + ni) * 512 + rdo);
#pragma unroll
        for (int mi = 0; mi < 4; ++mi)
            af[mi] = *(const bf16x8*)(At + (wr * 8 + mi) * 512 + rdo);
        __builtin_amdgcn_s_setprio(1);
#pragma unroll
        for (int mi = 0; mi < 4; ++mi)
#pragma unroll
            for (int ni = 0; ni < 4; ++ni)
                acc[mi][ni] = __builtin_amdgcn_mfma_f32_16x16x32_bf16(
                    af[mi], bfr[ni], acc[mi][ni], 0, 0, 0);
        __builtin_amdgcn_s_setprio(0);
        __builtin_amdgcn_s_barrier();
        __builtin_amdgcn_sched_barrier(0);

        // ---- phase B: M-frag rows 4-7 (+ stage B of t+3) ----
        if (t + 3 < 32) STAGE(t + 3, true);
#pragma unroll
        for (int mi = 0; mi < 4; ++mi)
            af[mi] = *(const bf16x8*)(At + (wr * 8 + 4 + mi) * 512 + rdo);
        __builtin_amdgcn_s_setprio(1);
#pragma unroll
        for (int mi = 0; mi < 4; ++mi)
#pragma unroll
            for (int ni = 0; ni < 4; ++ni)
                acc[4 + mi][ni] = __builtin_amdgcn_mfma_f32_16x16x32_bf16(
                    af[mi], bfr[ni], acc[4 + mi][ni], 0, 0, 0);
        __builtin_amdgcn_s_setprio(0);
    }

    // ---- epilogue: bias + activation, f16 store ----
    // C/D map: col = lane&15, row = (lane>>4)*4 + r
#pragma unroll
    for (int ni = 0; ni < 4; ++ni) {
        int gcol = n0 + wc * 64 + ni * 16 + lr;
        bool is_g = ((gcol >> 10) == 2);
        float bv = bias[gcol];
#pragma unroll
        for (int mi = 0; mi < 8; ++mi) {
            int grow = m0 + wr * 128 + mi * 16 + lg * 4;
#pragma unroll
            for (int r = 0; r < 4; ++r) {
                float v = acc[mi][ni][r] + bv;
                float e;
                if (is_g) e = 1.f - 2.f / (1.f + __expf(2.f * v));   // tanh
                else      e = 1.f / (1.f + __expf(-v));              // sigmoid
                gates[(size_t)(grow + r) * FOURH + gcol] = (_Float16)e;
            }
        }
    }
}

// ---------- kernel 4: recurrence, burst-8 prefetch, one thread per (b,h) ------
__global__ __launch_bounds__(256) void lstm_recur(
    const _Float16* __restrict__ gates,  // [64*chunk][4096] activated f16
    float* __restrict__ out,             // d_out base (f32)
    float* __restrict__ cstate,          // [65536]
    int chunk, int s0) {
    int t = blockIdx.x * 256 + threadIdx.x;  // 0..65535
    int b = t >> 10, h = t & 1023;
    float c = (s0 == 0) ? 0.f : cstate[t];
    const _Float16* gp = gates + (size_t)b * chunk * FOURH + h;
    float* op = out + (size_t)(b * SEQ + s0) * HS + h;
    float hv = 0.f;
    for (int sl = 0; sl < chunk; sl += 8) {
        float iv[8], fv[8], gv[8], ov[8];
#pragma unroll
        for (int u = 0; u < 8; ++u) {
            const _Float16* q = gp + (size_t)(sl + u) * FOURH;
            iv[u] = (float)q[0];
            fv[u] = (float)q[1024];
            gv[u] = (float)q[2048];
            ov[u] = (float)q[3072];
        }
#pragma unroll
        for (int u = 0; u < 8; ++u) {
            c = fv[u] * c + iv[u] * gv[u];
            float th = 1.f - 2.f / (1.f + __expf(2.f * c));
            hv = ov[u] * th;
            op[(size_t)(sl + u) * HS] = hv;
        }
    }
    cstate[t] = c;
    if (s0 + chunk == SEQ) {
        out[(size_t)BATCH * SEQ * HS + t] = hv;                      // h_T
        out[(size_t)BATCH * SEQ * HS + BATCH * HS + t] = c;          // c_T
    }
}

// ---------- launcher ----------
extern "C" void kernel_launch(void* const* d_in, const int* in_sizes, int n_in,
                              void* d_out, int out_size, void* d_ws, size_t ws_size,
                              hipStream_t stream) {
    const float* x    = (const float*)d_in[0];
    const float* U    = (const float*)d_in[1];
    const float* bias = (const float*)d_in[2];
    float* out = (float*)d_out;
    char*  ws  = (char*)d_ws;

    // ws layout
    unsigned short* Xb = (unsigned short*)ws;                   // 64MB  bf16 x
    unsigned short* Ut = (unsigned short*)(ws + 67108864);      // 8MB   bf16 U^T
    float* cstate      = (float*)(ws + 75497472);               // 256KB
    _Float16* gates    = (_Float16*)(ws + 75759616);            // chunk*0.5MB
    const size_t fixed = 75759616;

    int chunk = 512;
    while (chunk > 4 && fixed + (size_t)BATCH * chunk * FOURH * 2 > ws_size)
        chunk >>= 1;
    int lg2 = 31 - __builtin_clz(chunk);

    convert_x<<<2048, 256, 0, stream>>>(x, Xb, (long)BATCH * SEQ * HS / 8);
    transpose_u<<<4096, 256, 0, stream>>>(U, Ut);

    for (int s0 = 0; s0 < SEQ; s0 += chunk) {
        int mtiles = (BATCH * chunk) / 256;
        gemm_gates8<<<mtiles * 16, 512, 0, stream>>>(Xb, Ut, bias, gates, lg2, s0);
        lstm_recur<<<256, 256, 0, stream>>>(gates, out, cstate, chunk, s0);
    }
}

// Round 4
// 482.207 us; speedup vs baseline: 1.6927x; 1.1923x over previous
//
#include <hip/hip_runtime.h>
#include <hip/hip_bf16.h>
#include <stdint.h>

// ---------- types ----------
typedef __bf16 bf16x8 __attribute__((ext_vector_type(8)));
typedef float  f32x4  __attribute__((ext_vector_type(4)));
typedef unsigned short u16x8 __attribute__((ext_vector_type(8)));

#define HS    1024     // hidden size
#define FOURH 4096
#define SEQ   512
#define BATCH 64

#define BAR() asm volatile("s_barrier" ::: "memory")
#define VMW(n) asm volatile("s_waitcnt vmcnt(" #n ")" ::: "memory")

// manual round-to-nearest-even f32 -> bf16 bits
__device__ __forceinline__ unsigned short f2bf(float f) {
    unsigned u = __builtin_bit_cast(unsigned, f);
    u = (u + 0x7FFFu + ((u >> 16) & 1u)) >> 16;
    return (unsigned short)u;
}

__device__ __forceinline__ void gload_lds16(const void* g, void* l) {
    __builtin_amdgcn_global_load_lds(
        (const __attribute__((address_space(1))) void*)g,
        (__attribute__((address_space(3))) void*)l, 16, 0, 0);
}

// ---------- kernel 1: x (f32) -> Xb (bf16) ----------
__global__ __launch_bounds__(256) void convert_x(const float* __restrict__ x,
                                                 unsigned short* __restrict__ xb,
                                                 long n8) {
    long i = (long)blockIdx.x * blockDim.x + threadIdx.x;
    long stride = (long)gridDim.x * blockDim.x;
    for (; i < n8; i += stride) {
        const float4* p = (const float4*)(x + i * 8);
        float4 a = p[0], b = p[1];
        u16x8 o;
        o[0] = f2bf(a.x); o[1] = f2bf(a.y); o[2] = f2bf(a.z); o[3] = f2bf(a.w);
        o[4] = f2bf(b.x); o[5] = f2bf(b.y); o[6] = f2bf(b.z); o[7] = f2bf(b.w);
        *(u16x8*)(xb + i * 8) = o;
    }
}

// ---------- kernel 2: U [1024][4096] f32 -> Ut [4096][1024] bf16 ----------
__global__ __launch_bounds__(256) void transpose_u(const float* __restrict__ U,
                                                   unsigned short* __restrict__ Ut) {
    __shared__ float tile[32][33];
    int bx = blockIdx.x;            // 4096 blocks
    int tn = bx >> 5;               // n tile
    int tk = bx & 31;               // k tile
    int c = threadIdx.x & 31;
    int r = threadIdx.x >> 5;
#pragma unroll
    for (int i = 0; i < 4; ++i) {
        int k = tk * 32 + r + i * 8;
        tile[r + i * 8][c] = U[(size_t)k * FOURH + tn * 32 + c];
    }
    __syncthreads();
#pragma unroll
    for (int i = 0; i < 4; ++i) {
        int nl = r + i * 8;
        Ut[(size_t)(tn * 32 + nl) * HS + tk * 32 + c] = f2bf(tile[c][nl]);
    }
}

// ---------- kernel 3: 256x256 lookahead-1 fragment-pipelined bf16 GEMM --------
// BM=BN=256, BK=32 (32 K-tiles), 512 thr = 8 waves (2M x 4N), ring-4 LDS slots,
// fragments for interval i+1 read during interval i, vmcnt(8), setprio,
// st_16x32 swizzle, LDS-staged coalesced f16 epilogue.
__global__ __launch_bounds__(512, 2) void gemm_gates8(
    const unsigned short* __restrict__ Xb,   // [B*S][1024] bf16
    const unsigned short* __restrict__ Ut,   // [4096][1024] bf16
    const float* __restrict__ bias,          // [4096]
    _Float16* __restrict__ gates,            // [BATCH*chunk][4096] activated f16
    int lg2chunk, int s0) {
    __shared__ unsigned short LDSU[65536];   // 128KB: A slots [4][8192], B at +32768

    // T1: XCD-aware block swizzle (nwg multiple of 8)
    int nwg = gridDim.x;
    int bid = blockIdx.x;
    int wg = (bid & 7) * (nwg >> 3) + (bid >> 3);
    int mt = wg >> 4;            // 16 n-tiles (4096/256)
    int nt = wg & 15;

    int tid = threadIdx.x;
    int w = tid >> 6, l = tid & 63;
    int wr = w >> 2, wc = w & 3;       // wave grid 2 (M) x 4 (N)
    int lr = l & 15, lg = l >> 4;

    const int m0 = mt * 256, n0 = nt * 256;
    const int cmask = (1 << lg2chunk) - 1;

    // ds_read offset within a 16x32 subtile (ushort units), st_16x32 swizzle
    const int rdo = lr * 32 + ((lg * 8) ^ ((lr & 8) << 1));

    // staging lane geometry
    const int srow = l >> 2;
    const int skin = ((l & 3) * 8) ^ (((l >> 5) & 1) << 4);

    const unsigned short* pA[2];
    const unsigned short* pB[2];
#pragma unroll
    for (int j = 0; j < 2; ++j) {
        int row = (w * 2 + j) * 16 + srow;       // 0..255
        int mrow = m0 + row;
        int b = mrow >> lg2chunk, sl = mrow & cmask;
        pA[j] = Xb + (size_t)(b * SEQ + s0 + sl) * HS + skin;
        pB[j] = Ut + (size_t)(n0 + row) * HS + skin;
    }

    f32x4 acc[8][4];
#pragma unroll
    for (int mi = 0; mi < 8; ++mi)
#pragma unroll
        for (int ni = 0; ni < 4; ++ni) acc[mi][ni] = 0.f;

    bf16x8 afa[4], afb[4], bfe[4], bfo[4];

    // stage both halves (A,B) of K-tile t into slot t&3 (4 loads/thread)
    auto STAGE = [&](int t) {
        int sl = (t & 3) * 8192;
        int ko = t * 32;
        unsigned short* da = &LDSU[sl + (w * 2) * 512];
        gload_lds16(pA[0] + ko, da);
        gload_lds16(pA[1] + ko, da + 512);
        unsigned short* db = &LDSU[32768 + sl + (w * 2) * 512];
        gload_lds16(pB[0] + ko, db);
        gload_lds16(pB[1] + ko, db + 512);
    };
    auto rdA0 = [&](int t, bf16x8* d) {
        const unsigned short* p = &LDSU[(t & 3) * 8192];
#pragma unroll
        for (int mi = 0; mi < 4; ++mi)
            d[mi] = *(const bf16x8*)(p + (wr * 8 + mi) * 512 + rdo);
    };
    auto rdA1 = [&](int t, bf16x8* d) {
        const unsigned short* p = &LDSU[(t & 3) * 8192];
#pragma unroll
        for (int mi = 0; mi < 4; ++mi)
            d[mi] = *(const bf16x8*)(p + (wr * 8 + 4 + mi) * 512 + rdo);
    };
    auto rdB = [&](int t, bf16x8* d) {
        const unsigned short* p = &LDSU[32768 + (t & 3) * 8192];
#pragma unroll
        for (int ni = 0; ni < 4; ++ni)
            d[ni] = *(const bf16x8*)(p + (wc * 4 + ni) * 512 + rdo);
    };
    auto mmL = [&](bf16x8* a, bf16x8* b) {
        __builtin_amdgcn_s_setprio(1);
#pragma unroll
        for (int mi = 0; mi < 4; ++mi)
#pragma unroll
            for (int ni = 0; ni < 4; ++ni)
                acc[mi][ni] = __builtin_amdgcn_mfma_f32_16x16x32_bf16(
                    a[mi], b[ni], acc[mi][ni], 0, 0, 0);
        __builtin_amdgcn_s_setprio(0);
    };
    auto mmH = [&](bf16x8* a, bf16x8* b) {
        __builtin_amdgcn_s_setprio(1);
#pragma unroll
        for (int mi = 0; mi < 4; ++mi)
#pragma unroll
            for (int ni = 0; ni < 4; ++ni)
                acc[4 + mi][ni] = __builtin_amdgcn_mfma_f32_16x16x32_bf16(
                    a[mi], b[ni], acc[4 + mi][ni], 0, 0, 0);
        __builtin_amdgcn_s_setprio(0);
    };

    // prologue: tiles 0,1,2 in flight; fragments of tile 0 pre-read
    STAGE(0); STAGE(1); STAGE(2);
    VMW(8); BAR();
    rdA0(0, afa); rdB(0, bfe);

    for (int tt = 0; tt < 14; ++tt) {
        int t = tt * 2;                 // even tile
        STAGE(t + 3);
        rdA1(t, afb);
        mmL(afa, bfe);
        VMW(8); BAR();
        rdA0(t + 1, afa); rdB(t + 1, bfo);
        mmH(afb, bfe);
        BAR();
        // odd tile t+1
        STAGE(t + 4);
        rdA1(t + 1, afb);
        mmL(afa, bfo);
        VMW(8); BAR();
        rdA0(t + 2, afa); rdB(t + 2, bfe);
        mmH(afb, bfo);
        BAR();
    }
    // t = 28 (even): last tile that stages
    STAGE(31);
    rdA1(28, afb);
    mmL(afa, bfe);
    VMW(8); BAR();
    rdA0(29, afa); rdB(29, bfo);
    mmH(afb, bfe);
    BAR();
    VMW(0); BAR();
    // tiles 29..31: all LDS resident, straight-line
    rdA1(29, afb); mmL(afa, bfo);
    rdA0(30, afa); rdB(30, bfe); mmH(afb, bfo);
    rdA1(30, afb); mmL(afa, bfe);
    rdA0(31, afa); rdB(31, bfo); mmH(afb, bfe);
    rdA1(31, afb); mmL(afa, bfo);
    mmH(afb, bfo);

    // ---- epilogue: act -> f16 via LDS, then coalesced 16B global stores ----
    BAR();
    _Float16* T = (_Float16*)LDSU;   // [256][256] f16, col ^ ((row>>2&3)<<4)
#pragma unroll
    for (int ni = 0; ni < 4; ++ni) {
        int col = wc * 64 + ni * 16 + lr;
        int gcol = n0 + col;
        bool is_g = ((gcol >> 10) == 2);
        float bv = bias[gcol];
#pragma unroll
        for (int mi = 0; mi < 8; ++mi) {
#pragma unroll
            for (int r = 0; r < 4; ++r) {
                int row = wr * 128 + mi * 16 + lg * 4 + r;
                float v = acc[mi][ni][r] + bv;
                float e;
                if (is_g) e = 1.f - 2.f / (1.f + __expf(2.f * v));   // tanh
                else      e = 1.f / (1.f + __expf(-v));              // sigmoid
                T[row * 256 + (col ^ (((row >> 2) & 3) << 4))] = (_Float16)e;
            }
        }
    }
    BAR();
#pragma unroll
    for (int p = 0; p < 16; ++p) {
        int q = p * 512 + tid;           // 16B-slot id, 0..8191
        int row = q >> 5, s = q & 31;
        int cs = (s * 8) ^ (((row >> 2) & 3) << 4);
        uint4 val = *(const uint4*)(T + row * 256 + cs);
        *(uint4*)(gates + (size_t)(m0 + row) * FOURH + n0 + s * 8) = val;
    }
}

// ---------- kernel 4: recurrence, burst-8 prefetch, one thread per (b,h) ------
__global__ __launch_bounds__(256) void lstm_recur(
    const _Float16* __restrict__ gates,  // [64*chunk][4096] activated f16
    float* __restrict__ out,             // d_out base (f32)
    float* __restrict__ cstate,          // [65536]
    int chunk, int s0) {
    int t = blockIdx.x * 256 + threadIdx.x;  // 0..65535
    int b = t >> 10, h = t & 1023;
    float c = (s0 == 0) ? 0.f : cstate[t];
    const _Float16* gp = gates + (size_t)b * chunk * FOURH + h;
    float* op = out + (size_t)(b * SEQ + s0) * HS + h;
    float hv = 0.f;
    for (int sl = 0; sl < chunk; sl += 8) {
        float iv[8], fv[8], gv[8], ov[8];
#pragma unroll
        for (int u = 0; u < 8; ++u) {
            const _Float16* q = gp + (size_t)(sl + u) * FOURH;
            iv[u] = (float)q[0];
            fv[u] = (float)q[1024];
            gv[u] = (float)q[2048];
            ov[u] = (float)q[3072];
        }
#pragma unroll
        for (int u = 0; u < 8; ++u) {
            c = fv[u] * c + iv[u] * gv[u];
            float th = 1.f - 2.f / (1.f + __expf(2.f * c));
            hv = ov[u] * th;
            op[(size_t)(sl + u) * HS] = hv;
        }
    }
    cstate[t] = c;
    if (s0 + chunk == SEQ) {
        out[(size_t)BATCH * SEQ * HS + t] = hv;                      // h_T
        out[(size_t)BATCH * SEQ * HS + BATCH * HS + t] = c;          // c_T
    }
}

// ---------- launcher ----------
extern "C" void kernel_launch(void* const* d_in, const int* in_sizes, int n_in,
                              void* d_out, int out_size, void* d_ws, size_t ws_size,
                              hipStream_t stream) {
    const float* x    = (const float*)d_in[0];
    const float* U    = (const float*)d_in[1];
    const float* bias = (const float*)d_in[2];
    float* out = (float*)d_out;
    char*  ws  = (char*)d_ws;

    // ws layout
    unsigned short* Xb = (unsigned short*)ws;                   // 64MB  bf16 x
    unsigned short* Ut = (unsigned short*)(ws + 67108864);      // 8MB   bf16 U^T
    float* cstate      = (float*)(ws + 75497472);               // 256KB
    _Float16* gates    = (_Float16*)(ws + 75759616);            // chunk*0.5MB
    const size_t fixed = 75759616;

    int chunk = 512;
    while (chunk > 4 && fixed + (size_t)BATCH * chunk * FOURH * 2 > ws_size)
        chunk >>= 1;
    int lg2 = 31 - __builtin_clz(chunk);

    convert_x<<<2048, 256, 0, stream>>>(x, Xb, (long)BATCH * SEQ * HS / 8);
    transpose_u<<<4096, 256, 0, stream>>>(U, Ut);

    for (int s0 = 0; s0 < SEQ; s0 += chunk) {
        int mtiles = (BATCH * chunk) / 256;
        gemm_gates8<<<mtiles * 16, 512, 0, stream>>>(Xb, Ut, bias, gates, lg2, s0);
        lstm_recur<<<256, 256, 0, stream>>>(gates, out, cstate, chunk, s0);
    }
}